// Round 11
// baseline (161.863 us; speedup 1.0000x reference)
//
#include <hip/hip_runtime.h>
#include <hip/hip_bf16.h>
#include <math.h>

// Problem constants
#define BB 8
#define TT 16
#define PP 14
#define LL 196      // P*P
#define HH 16
#define DD 64
#define DM 1024     // H*D
#define NS 16
#define T2 256      // T*T
#define LP1 197

using bf16x8 = __attribute__((ext_vector_type(8))) short;
using f32x4  = __attribute__((ext_vector_type(4))) float;

__device__ __forceinline__ float dot4(float4 a, float4 b) {
    return a.x*b.x + a.y*b.y + a.z*b.z + a.w*b.w;
}

// round-to-nearest-even bf16 pack of two finite fp32
__device__ __forceinline__ uint32_t pkbf(float lo, float hi) {
    uint32_t a = __builtin_bit_cast(uint32_t, lo);
    uint32_t b = __builtin_bit_cast(uint32_t, hi);
    a += 0x7FFFu + ((a >> 16) & 1u);
    b += 0x7FFFu + ((b >> 16) & 1u);
    return (a >> 16) | (b & 0xFFFF0000u);
}

// split pair (x,y) into hi/lo bf16 words: x ~= hi.x + lo.x exactly to ~2^-18
__device__ __forceinline__ void split2(float x, float y, uint32_t* h, uint32_t* lo) {
    const uint32_t hh = pkbf(x, y);
    const float hx = __builtin_bit_cast(float, hh << 16);
    const float hy = __builtin_bit_cast(float, hh & 0xFFFF0000u);
    *h = hh;
    *lo = pkbf(x - hx, y - hy);
}

__device__ __forceinline__ void pksplit(float4 p, float4 q, bf16x8& hi, bf16x8& lo) {
    uint32_t uh[4], ul[4];
    split2(p.x, p.y, &uh[0], &ul[0]);
    split2(p.z, p.w, &uh[1], &ul[1]);
    split2(q.x, q.y, &uh[2], &ul[2]);
    split2(q.z, q.w, &uh[3], &ul[3]);
    struct U4 { uint32_t v[4]; } th, tl;
    th.v[0] = uh[0]; th.v[1] = uh[1]; th.v[2] = uh[2]; th.v[3] = uh[3];
    tl.v[0] = ul[0]; tl.v[1] = ul[1]; tl.v[2] = ul[2]; tl.v[3] = ul[3];
    hi = __builtin_bit_cast(bf16x8, th);
    lo = __builtin_bit_cast(bf16x8, tl);
}

// ---------------------------------------------------------------------------
// Kernel 0: pre-split syno (16x1024 fp32) into hi/lo bf16 pair-words.
// ---------------------------------------------------------------------------
__global__ __launch_bounds__(256) void kprep(
        const float* __restrict__ syno,
        uint32_t* __restrict__ synoHi, uint32_t* __restrict__ synoLo) {
    const int i = blockIdx.x * 256 + threadIdx.x;   // 0..8191
    const float x = syno[2 * i], y = syno[2 * i + 1];
    uint32_t h, lo;
    split2(x, y, &h, &lo);
    synoHi[i] = h;
    synoLo[i] = lo;
}

// ---------------------------------------------------------------------------
// Kernel 1 (v7): 1024-thread blocks, 16 waves, 2 channel-iterations per wave
// (4x shorter dependent-load chain than v6). Waves 0-7 = q heads (Gram only),
// waves 8-15 = k heads (Gram + fused SL). Single conv pass over
// lds_c[32][260]; conv split 4 ch-groups x 256 pixels, reduced via cpart.
// launch_bounds(1024,8): VGPR<=64 -> 2 blocks/CU = 32 waves (full residency).
// Math identical to the verified v5/v6 kernels; only work ownership changed.
// ---------------------------------------------------------------------------
__global__ __launch_bounds__(1024, 8) void k1_temporal(
        const float* __restrict__ qin, const float* __restrict__ kin,
        const float* __restrict__ tw,  const float* __restrict__ tbv,
        const uint32_t* __restrict__ synoHi, const uint32_t* __restrict__ synoLo,
        float* __restrict__ affRaw, float* __restrict__ SLout) {
    __shared__ __align__(16) float lds_c[32 * 260];   // [ch][pix], pad 4
    __shared__ __align__(16) float sl_part[8][16][16];
    __shared__ __align__(16) float cpart[4][256];

    const int bid = blockIdx.x, b = bid / LL, l = bid % LL;
    const int tid = threadIdx.x, wid = tid >> 6, lane = tid & 63;
    const int mrow = lane & 15;            // A-fragment row = frame
    const int g = lane >> 4;               // k-chunk group
    const int colb = lane & 15;
    const bool kside = (wid >= 8);
    const float* sp2 = kside ? kin : qin;
    const size_t rowbase = ((size_t)(b*TT + mrow)*LP1 + 1 + l)*DM + g*8;

    f32x4 acc_sl = {0.f, 0.f, 0.f, 0.f};

    #pragma unroll
    for (int it = 0; it < 2; ++it) {
        const int hd = ((wid & 7) << 1) + it;       // head 0..15
        const float* base = sp2 + rowbase + (size_t)hd * DD;
        const float4 a0 = *reinterpret_cast<const float4*>(base);
        const float4 a1 = *reinterpret_cast<const float4*>(base + 4);
        const float4 a2 = *reinterpret_cast<const float4*>(base + 32);
        const float4 a3 = *reinterpret_cast<const float4*>(base + 36);
        bf16x8 h1, l1, h2, l2;
        pksplit(a0, a1, h1, l1);
        pksplit(a2, a3, h2, l2);
        f32x4 acc = {0.f, 0.f, 0.f, 0.f};
        acc = __builtin_amdgcn_mfma_f32_16x16x32_bf16(h1, h1, acc, 0, 0, 0);
        acc = __builtin_amdgcn_mfma_f32_16x16x32_bf16(h1, l1, acc, 0, 0, 0);
        acc = __builtin_amdgcn_mfma_f32_16x16x32_bf16(l1, h1, acc, 0, 0, 0);
        acc = __builtin_amdgcn_mfma_f32_16x16x32_bf16(h2, h2, acc, 0, 0, 0);
        acc = __builtin_amdgcn_mfma_f32_16x16x32_bf16(h2, l2, acc, 0, 0, 0);
        acc = __builtin_amdgcn_mfma_f32_16x16x32_bf16(l2, h2, acc, 0, 0, 0);
        if (kside) {
            const int off = colb * 512 + hd * 32 + g * 4;
            const bf16x8 sh1 = *reinterpret_cast<const bf16x8*>(synoHi + off);
            const bf16x8 sv1 = *reinterpret_cast<const bf16x8*>(synoLo + off);
            const bf16x8 sh2 = *reinterpret_cast<const bf16x8*>(synoHi + off + 16);
            const bf16x8 sv2 = *reinterpret_cast<const bf16x8*>(synoLo + off + 16);
            acc_sl = __builtin_amdgcn_mfma_f32_16x16x32_bf16(h1, sh1, acc_sl, 0, 0, 0);
            acc_sl = __builtin_amdgcn_mfma_f32_16x16x32_bf16(h1, sv1, acc_sl, 0, 0, 0);
            acc_sl = __builtin_amdgcn_mfma_f32_16x16x32_bf16(l1, sh1, acc_sl, 0, 0, 0);
            acc_sl = __builtin_amdgcn_mfma_f32_16x16x32_bf16(h2, sh2, acc_sl, 0, 0, 0);
            acc_sl = __builtin_amdgcn_mfma_f32_16x16x32_bf16(h2, sv2, acc_sl, 0, 0, 0);
            acc_sl = __builtin_amdgcn_mfma_f32_16x16x32_bf16(l2, sh2, acc_sl, 0, 0, 0);
        }
        // softmax over cols (keys); lane holds S[row=g*4+r][col=colb]
        const float x0 = acc[0]*0.125f, x1 = acc[1]*0.125f;
        const float x2 = acc[2]*0.125f, x3 = acc[3]*0.125f;
        float m0 = x0, m1 = x1, m2 = x2, m3 = x3;
        #pragma unroll
        for (int msk = 1; msk < 16; msk <<= 1) {
            m0 = fmaxf(m0, __shfl_xor(m0, msk, 64));
            m1 = fmaxf(m1, __shfl_xor(m1, msk, 64));
            m2 = fmaxf(m2, __shfl_xor(m2, msk, 64));
            m3 = fmaxf(m3, __shfl_xor(m3, msk, 64));
        }
        const float e0 = __expf(x0 - m0), e1 = __expf(x1 - m1);
        const float e2 = __expf(x2 - m2), e3 = __expf(x3 - m3);
        float s0 = e0, s1 = e1, s2 = e2, s3 = e3;
        #pragma unroll
        for (int msk = 1; msk < 16; msk <<= 1) {
            s0 += __shfl_xor(s0, msk, 64);
            s1 += __shfl_xor(s1, msk, 64);
            s2 += __shfl_xor(s2, msk, 64);
            s3 += __shfl_xor(s3, msk, 64);
        }
        const int ch = (kside ? 16 : 0) + hd;
        float* cp = lds_c + ch * 260;
        cp[(g*4 + 0)*16 + colb] = e0 / s0;
        cp[(g*4 + 1)*16 + colb] = e1 / s1;
        cp[(g*4 + 2)*16 + colb] = e2 / s2;
        cp[(g*4 + 3)*16 + colb] = e3 / s3;
    }
    if (kside) {
        #pragma unroll
        for (int r = 0; r < 4; ++r)
            sl_part[wid - 8][g * 4 + r][colb] = acc_sl[r];
    }
    __syncthreads();

    // conv partials: thread = (grp, pix); 8 channels per group, 9 taps
    const int pix = tid & 255, grp = tid >> 8;
    const int oq = pix >> 4, ok = pix & 15;
    float accv = 0.f;
    #pragma unroll
    for (int ky = 0; ky < 3; ++ky) {
        const int iq = oq + ky - 1;
        if (iq < 0 || iq > 15) continue;
        #pragma unroll
        for (int kx = 0; kx < 3; ++kx) {
            const int ik = ok + kx - 1;
            if (ik < 0 || ik > 15) continue;
            const int p2 = iq * 16 + ik;
            #pragma unroll
            for (int c = 0; c < 8; ++c) {
                const int ch = grp * 8 + c;
                accv += lds_c[ch * 260 + p2] * tw[ch * 9 + ky * 3 + kx];
            }
        }
    }
    cpart[grp][pix] = accv;
    // SL reduce over the 8 k-waves (sl_part ready since the barrier)
    if (tid < 256) {
        const int t = tid >> 4, qq = tid & 15;
        float s = 0.f;
        #pragma unroll
        for (int w8 = 0; w8 < 8; ++w8) s += sl_part[w8][t][qq];
        SLout[((size_t)(b * TT + t) * NS + qq) * LL + l] = s * 0.03125f;
    }
    __syncthreads();
    if (tid < 256) {
        affRaw[(size_t)bid * T2 + tid] = tbv[0] + cpart[0][tid] + cpart[1][tid]
                                       + cpart[2][tid] + cpart[3][tid];
    }
}

// ---------------------------------------------------------------------------
// Kernel 2: LayerNorm + MLP (gelu exact) + residual. 4 rows per block.
// ---------------------------------------------------------------------------
__global__ __launch_bounds__(256) void k2_mlp(
        const float* __restrict__ affRaw,
        const float* __restrict__ lng, const float* __restrict__ lnb,
        const float* __restrict__ w1, const float* __restrict__ b1,
        const float* __restrict__ w2, const float* __restrict__ b2,
        float* __restrict__ affRes) {
    __shared__ __align__(16) float lx[4 * 256];
    __shared__ __align__(16) float lln[4 * 256];
    __shared__ __align__(16) float lg[4 * 256];
    const int tid = threadIdx.x;
    const int wave = tid >> 6, lane = tid & 63;
    const int i0 = blockIdx.x * 4;
    {
        const float* xr = affRaw + (size_t)(i0 + wave) * 256;
        float4 x = reinterpret_cast<const float4*>(xr)[lane];
        float sm = x.x + x.y + x.z + x.w;
        float ss = x.x * x.x + x.y * x.y + x.z * x.z + x.w * x.w;
        #pragma unroll
        for (int m = 1; m < 64; m <<= 1) {
            sm += __shfl_xor(sm, m, 64);
            ss += __shfl_xor(ss, m, 64);
        }
        const float mean = sm * (1.f / 256.f);
        const float var = ss * (1.f / 256.f) - mean * mean;
        const float inv = rsqrtf(var + 1e-5f);
        const float4 g4 = reinterpret_cast<const float4*>(lng)[lane];
        const float4 bb = reinterpret_cast<const float4*>(lnb)[lane];
        float4 ln;
        ln.x = (x.x - mean) * inv * g4.x + bb.x;
        ln.y = (x.y - mean) * inv * g4.y + bb.y;
        ln.z = (x.z - mean) * inv * g4.z + bb.z;
        ln.w = (x.w - mean) * inv * g4.w + bb.w;
        reinterpret_cast<float4*>(lx + wave * 256)[lane] = x;
        reinterpret_cast<float4*>(lln + wave * 256)[lane] = ln;
    }
    __syncthreads();
    const int j = tid;
    float a0 = 0.f, a1 = 0.f, a2 = 0.f, a3 = 0.f;
    {
        const float4* wr = reinterpret_cast<const float4*>(w1 + (size_t)j * 256);
        const float4* l0 = reinterpret_cast<const float4*>(lln);
        const float4* l1 = reinterpret_cast<const float4*>(lln + 256);
        const float4* l2 = reinterpret_cast<const float4*>(lln + 512);
        const float4* l3 = reinterpret_cast<const float4*>(lln + 768);
        #pragma unroll 8
        for (int m4 = 0; m4 < 64; ++m4) {
            const float4 w = wr[m4];
            a0 += dot4(w, l0[m4]); a1 += dot4(w, l1[m4]);
            a2 += dot4(w, l2[m4]); a3 += dot4(w, l3[m4]);
        }
    }
    const float bj = b1[j];
    const float kInvSqrt2 = 0.70710678118654752f;
    float h0 = a0 + bj, h1 = a1 + bj, h2 = a2 + bj, h3 = a3 + bj;
    lg[0 * 256 + j] = 0.5f * h0 * (1.f + erff(h0 * kInvSqrt2));
    lg[1 * 256 + j] = 0.5f * h1 * (1.f + erff(h1 * kInvSqrt2));
    lg[2 * 256 + j] = 0.5f * h2 * (1.f + erff(h2 * kInvSqrt2));
    lg[3 * 256 + j] = 0.5f * h3 * (1.f + erff(h3 * kInvSqrt2));
    __syncthreads();
    a0 = a1 = a2 = a3 = 0.f;
    {
        const float4* wr = reinterpret_cast<const float4*>(w2 + (size_t)j * 256);
        const float4* l0 = reinterpret_cast<const float4*>(lg);
        const float4* l1 = reinterpret_cast<const float4*>(lg + 256);
        const float4* l2 = reinterpret_cast<const float4*>(lg + 512);
        const float4* l3 = reinterpret_cast<const float4*>(lg + 768);
        #pragma unroll 8
        for (int m4 = 0; m4 < 64; ++m4) {
            const float4 w = wr[m4];
            a0 += dot4(w, l0[m4]); a1 += dot4(w, l1[m4]);
            a2 += dot4(w, l2[m4]); a3 += dot4(w, l3[m4]);
        }
    }
    const float b2j = b2[j];
    affRes[(size_t)(i0 + 0) * 256 + j] = lx[0 * 256 + j] + a0 + b2j;
    affRes[(size_t)(i0 + 1) * 256 + j] = lx[1 * 256 + j] + a1 + b2j;
    affRes[(size_t)(i0 + 2) * 256 + j] = lx[2 * 256 + j] + a2 + b2j;
    affRes[(size_t)(i0 + 3) * 256 + j] = lx[3 * 256 + j] + a3 + b2j;
}

// ---------------------------------------------------------------------------
// Kernel 3a: patch-grid 3x3 conv over 256 channels, split 64-ch per block.
// ---------------------------------------------------------------------------
__global__ __launch_bounds__(256) void k3a_pconv(
        const float* __restrict__ affRes, const float* __restrict__ pw,
        float* __restrict__ part) {
    __shared__ __align__(16) float lpw[576];
    const int b = blockIdx.x >> 2, cc = blockIdx.x & 3;
    const int tid = threadIdx.x;
    for (int idx = tid; idx < 576; idx += 256) {
        const int kk = idx / 64, c = idx & 63;
        lpw[kk * 64 + c] = pw[(size_t)(cc * 64 + c) * 9 + kk];
    }
    __syncthreads();
    if (tid < 196) {
        const int p1 = tid / 14, p2 = tid % 14;
        float s = 0.f;
        #pragma unroll
        for (int ky = 0; ky < 3; ++ky) {
            const int ip1 = p1 + ky - 1;
            if (ip1 < 0 || ip1 > 13) continue;
            #pragma unroll
            for (int kx = 0; kx < 3; ++kx) {
                const int ip2 = p2 + kx - 1;
                if (ip2 < 0 || ip2 > 13) continue;
                const float4* ar = reinterpret_cast<const float4*>(
                    affRes + (size_t)(b * LL + ip1 * 14 + ip2) * 256 + cc * 64);
                const float4* wr = reinterpret_cast<const float4*>(lpw + (ky * 3 + kx) * 64);
                #pragma unroll
                for (int c4 = 0; c4 < 16; ++c4) s += dot4(ar[c4], wr[c4]);
            }
        }
        part[(cc * 8 + b) * 196 + tid] = s;
    }
}

__global__ void k3b_yt(const float* __restrict__ part,
                       const float* __restrict__ pcb, float* __restrict__ out) {
    const int b = blockIdx.x, tid = threadIdx.x;
    if (tid < 196) {
        float s = pcb[0];
        #pragma unroll
        for (int cc = 0; cc < 4; ++cc) s += part[(cc * 8 + b) * 196 + tid];
        out[b * 196 + tid] = s;
    }
}

// Kernel 4b: softmax over l per (b,t,q) + sum over q -> WSUM[b,t,l]
__global__ __launch_bounds__(256) void k4b_softmax(
        const float* __restrict__ SL, float* __restrict__ WSUM) {
    __shared__ float lp[16 * 200];
    const int t = blockIdx.x, b = blockIdx.y;
    const int tid = threadIdx.x;
    const int qq = tid >> 4, j = tid & 15;
    const float* row = SL + (size_t)((b * TT + t) * NS + qq) * LL;
    float v[13];
    float m = -1e30f;
    #pragma unroll
    for (int i = 0; i < 13; ++i) {
        const int l = j + i * 16;
        v[i] = (l < LL) ? row[l] : -1e30f;
        m = fmaxf(m, v[i]);
    }
    #pragma unroll
    for (int msk = 1; msk < 16; msk <<= 1) m = fmaxf(m, __shfl_xor(m, msk, 64));
    float s = 0.f;
    #pragma unroll
    for (int i = 0; i < 13; ++i) {
        const int l = j + i * 16;
        v[i] = (l < LL) ? __expf(v[i] - m) : 0.f;
        s += v[i];
    }
    #pragma unroll
    for (int msk = 1; msk < 16; msk <<= 1) s += __shfl_xor(s, msk, 64);
    const float inv = 1.f / s;
    #pragma unroll
    for (int i = 0; i < 13; ++i) {
        const int l = j + i * 16;
        if (l < LL) lp[qq * 200 + l] = v[i] * inv;
    }
    __syncthreads();
    if (tid < LL) {
        float w = 0.f;
        #pragma unroll
        for (int qi = 0; qi < 16; ++qi) w += lp[qi * 200 + tid];
        WSUM[(size_t)(b * TT + t) * LL + tid] = w;
    }
}

// Kernel 4c: PS[bt][z][:] = sum over 98 rows of WSUM * v  (z-split over l)
__global__ __launch_bounds__(256) void k4c_vsum(
        const float* __restrict__ vin, const float* __restrict__ WSUM,
        float* __restrict__ PS) {
    __shared__ float lw[98];
    const int t = blockIdx.x, b = blockIdx.y, z = blockIdx.z;
    const int tid = threadIdx.x;
    const int bt = b * TT + t;
    if (tid < 98) lw[tid] = WSUM[(size_t)bt * LL + z * 98 + tid];
    __syncthreads();
    float4 acc = make_float4(0.f, 0.f, 0.f, 0.f);
    const float* vb = vin + ((size_t)bt * LP1 + 1 + z * 98) * DM + tid * 4;
    #pragma unroll 4
    for (int l = 0; l < 98; ++l) {
        const float4 v = *reinterpret_cast<const float4*>(vb + (size_t)l * DM);
        const float w = lw[l];
        acc.x += w * v.x; acc.y += w * v.y; acc.z += w * v.z; acc.w += w * v.w;
    }
    *reinterpret_cast<float4*>(PS + ((size_t)bt * 2 + z) * DM + tid * 4) = acc;
}

// Kernel 4d: y_s[b,w] = (1/256) * sum over 32 (t,z) partials
__global__ void k4d_ys(const float* __restrict__ PS, float* __restrict__ out) {
    const int i = blockIdx.x * 256 + threadIdx.x;   // 0..8191
    const int b = i >> 10, w = i & 1023;
    float s = 0.f;
    #pragma unroll
    for (int tz = 0; tz < 32; ++tz) s += PS[((size_t)b * 32 + tz) * DM + w];
    out[1568 + i] = s * (1.f / 256.f);
}

// ---------------------------------------------------------------------------
extern "C" void kernel_launch(void* const* d_in, const int* in_sizes, int n_in,
                              void* d_out, int out_size, void* d_ws, size_t ws_size,
                              hipStream_t stream) {
    const float* q    = (const float*)d_in[0];
    const float* k    = (const float*)d_in[1];
    const float* v    = (const float*)d_in[2];
    const float* syno = (const float*)d_in[3];
    const float* tw   = (const float*)d_in[4];
    const float* tbv  = (const float*)d_in[5];
    const float* lng  = (const float*)d_in[6];
    const float* lnb  = (const float*)d_in[7];
    const float* w1   = (const float*)d_in[8];
    const float* b1   = (const float*)d_in[9];
    const float* w2   = (const float*)d_in[10];
    const float* b2   = (const float*)d_in[11];
    const float* pw   = (const float*)d_in[12];
    const float* pcb  = (const float*)d_in[13];
    float* out = (float*)d_out;

    float* ws = (float*)d_ws;
    float* affRaw = ws;                 // 401408 floats (dead after k2)
    float* affRes = ws + 401408;        // 401408
    float* SL     = ws + 802816;        // 401408
    float* WSUM   = ws + 1204224;       // 25088
    float* part   = ws + 1229312;       // 6272
    uint32_t* synoHi = (uint32_t*)(ws + 1235584);   // 8192 u32
    uint32_t* synoLo = (uint32_t*)(ws + 1243776);   // 8192 u32
    float* PS     = ws;                 // 262144, aliases affRaw (k4c after k2)

    // syno pre-split (hi/lo bf16)
    hipLaunchKernelGGL(kprep, dim3(32), dim3(256), 0, stream, syno, synoHi, synoLo);
    // temporal path + fused spatial logits
    hipLaunchKernelGGL(k1_temporal, dim3(BB * LL), dim3(1024), 0, stream,
                       q, k, tw, tbv, synoHi, synoLo, affRaw, SL);
    hipLaunchKernelGGL(k2_mlp, dim3(392), dim3(256), 0, stream,
                       affRaw, lng, lnb, w1, b1, w2, b2, affRes);
    hipLaunchKernelGGL(k3a_pconv, dim3(32), dim3(256), 0, stream,
                       affRes, pw, part);
    hipLaunchKernelGGL(k3b_yt, dim3(8), dim3(256), 0, stream, part, pcb, out);
    // spatial path (k4a fused into k1)
    hipLaunchKernelGGL(k4b_softmax, dim3(16, 8), dim3(256), 0, stream, SL, WSUM);
    hipLaunchKernelGGL(k4c_vsum, dim3(16, 8, 2), dim3(256), 0, stream, v, WSUM, PS);
    hipLaunchKernelGGL(k4d_ys, dim3(32), dim3(256), 0, stream, PS, out);
}